// Round 7
// baseline (104.010 us; speedup 1.0000x reference)
//
#include <hip/hip_runtime.h>
#include <math.h>

#define NUM_ENT 10000
#define NUM_REL 230
#define R2      460
#define S_DIM   96
#define T_DIM   32
#define DIM     128
#define N_NBR   32768
#define Q_ENT   4096
#define E_EDGE  32768
#define B_TRI   1024
#define BN_EPS  1e-5f
#define CHUNK   64

typedef __attribute__((ext_vector_type(8))) short bf16x8;
typedef __attribute__((ext_vector_type(4))) float f32x4;

// f32 -> bf16 round-to-nearest-even
__device__ __forceinline__ unsigned short f2bf(float f) {
    unsigned int u = __float_as_uint(f);
    u = (u + 0x7FFFu + ((u >> 16) & 1u)) >> 16;
    return (unsigned short)u;
}

// X LDS swizzle (ushort units): breaks the 256B row stride for A-frag b128
// reads. XOR bits >=3 keep 4-ushort groups contiguous (8B stores ok).
__device__ __forceinline__ int XIDX(int m, int d) {
    return (m * DIM + d) ^ ((m & 7) << 3);
}

// ---------------------------------------------------------------------------
// K1 (k_front): blocks [0,460): W[r] f32 -> bf16 in per-lane MFMA fragment
//   order. Wfrag ushort offset: ((kk*4+wv)*2+h)*512 + lane*8 + j holds
//   bf16(W[r][32*kk + 8*(lane>>4) + j][32*wv + 16*h + (lane&15)]).
// block 460: rel_id LDS histogram (460 bins) + scan -> offsets[461] and
//   cursor copy cur_rel[460].
// block 461: pool_dst LDS histogram (4096 bins) + scan -> dst_off[4097] and
//   cursor copy cur_dst[4096].
// No global zeroing needed anywhere.
// ---------------------------------------------------------------------------
__global__ __launch_bounds__(256, 2) void k_front(
    const float* __restrict__ W, unsigned short* __restrict__ Wfrag,
    const int* __restrict__ rel, const int* __restrict__ pdst,
    int* __restrict__ offsets, int* __restrict__ cur_rel,
    int* __restrict__ dst_off, int* __restrict__ cur_dst)
{
    __shared__ __align__(16) char smem[65536];
    const int t = threadIdx.x;

    if (blockIdx.x == R2) {
        // ---- relation histogram + scan (460 bins, 256 threads)
        int* histr = (int*)smem;            // 512 ints (padded)
        int* ps    = (int*)(smem + 2048);   // 256 ints
        histr[t] = 0; histr[t + 256] = 0;
        __syncthreads();
        for (int i = t; i < N_NBR; i += 256) atomicAdd(&histr[rel[i]], 1);
        __syncthreads();
        const int h0 = histr[2 * t], h1 = histr[2 * t + 1];
        ps[t] = h0 + h1;
        __syncthreads();
        for (int off = 1; off < 256; off <<= 1) {
            int a = (t >= off) ? ps[t - off] : 0;
            __syncthreads();
            ps[t] += a;
            __syncthreads();
        }
        const int ex = (t > 0) ? ps[t - 1] : 0;
        if (2 * t <= R2) offsets[2 * t] = ex;
        if (2 * t < R2)  cur_rel[2 * t] = ex;
        if (2 * t + 1 <= R2) offsets[2 * t + 1] = ex + h0;
        if (2 * t + 1 < R2)  cur_rel[2 * t + 1] = ex + h0;
        return;
    }
    if (blockIdx.x == R2 + 1) {
        // ---- dst histogram + scan (4096 bins, 16/thread)
        int* histd = (int*)smem;             // 4096 ints
        int* ps    = (int*)(smem + 16384);   // 256 ints
        for (int j = t; j < 4096; j += 256) histd[j] = 0;
        __syncthreads();
        for (int i = t; i < E_EDGE; i += 256) atomicAdd(&histd[pdst[i]], 1);
        __syncthreads();
        const int base = t * 16;
        int lsumh = 0;
        #pragma unroll
        for (int j = 0; j < 16; ++j) lsumh += histd[base + j];
        ps[t] = lsumh;
        __syncthreads();
        for (int off = 1; off < 256; off <<= 1) {
            int a = (t >= off) ? ps[t - off] : 0;
            __syncthreads();
            ps[t] += a;
            __syncthreads();
        }
        int run = (t > 0) ? ps[t - 1] : 0;
        #pragma unroll
        for (int j = 0; j < 16; ++j) {
            dst_off[base + j] = run;
            cur_dst[base + j] = run;
            run += histd[base + j];
        }
        if (t == 255) dst_off[4096] = run;
        return;
    }

    // ---- Wfrag conversion for relation r
    const int r = blockIdx.x;
    float* Wl = (float*)smem;   // 64 KB
    {
        const float4* Wg = (const float4*)(W + (size_t)r * DIM * DIM);
        float4* Wl4 = (float4*)Wl;
        #pragma unroll
        for (int i = 0; i < 16; ++i)
            Wl4[t + i * 256] = Wg[t + i * 256];
    }
    __syncthreads();
    unsigned short* dst = Wfrag + (size_t)r * DIM * DIM;
    #pragma unroll
    for (int it = 0; it < 8; ++it) {
        const int id = t + it * 256;            // 0..2047
        const int lane = id & 63;
        const int h    = (id >> 6) & 1;
        const int wv   = (id >> 7) & 3;
        const int kk   = (id >> 9) & 3;
        const int n  = 32 * wv + 16 * h + (lane & 15);
        const int kb = 32 * kk + 8 * (lane >> 4);
        ushort4 lo, hi;
        lo.x = f2bf(Wl[(kb + 0) * DIM + n]);
        lo.y = f2bf(Wl[(kb + 1) * DIM + n]);
        lo.z = f2bf(Wl[(kb + 2) * DIM + n]);
        lo.w = f2bf(Wl[(kb + 3) * DIM + n]);
        hi.x = f2bf(Wl[(kb + 4) * DIM + n]);
        hi.y = f2bf(Wl[(kb + 5) * DIM + n]);
        hi.z = f2bf(Wl[(kb + 6) * DIM + n]);
        hi.w = f2bf(Wl[(kb + 7) * DIM + n]);
        *(ushort4*)&dst[id * 8]     = lo;
        *(ushort4*)&dst[id * 8 + 4] = hi;
    }
}

// ---------------------------------------------------------------------------
// K2: scatter: rel-sorted neighbor order (+rank) and dst-sorted edge order.
// Cursors were pre-initialized to the scan offsets by k_front.
// ---------------------------------------------------------------------------
__global__ void k_scatter(const int* __restrict__ rel,
                          int* __restrict__ cur_rel, int* __restrict__ order,
                          int* __restrict__ rank,
                          const int* __restrict__ pdst,
                          int* __restrict__ cur_dst, int* __restrict__ eorder) {
    int i = blockIdx.x * blockDim.x + threadIdx.x;
    if (i < N_NBR) {
        const int pos = atomicAdd(&cur_rel[rel[i]], 1);
        order[pos] = i;
        rank[i] = pos;
    }
    if (i < E_EDGE) {
        eorder[atomicAdd(&cur_dst[pdst[i]], 1)] = i;
    }
}

// ---------------------------------------------------------------------------
// K3: MFMA matvec. ONE BLOCK PER RELATION, looping 64-row chunks.
// X gathered as bf16 into swizzled LDS [64][128] (16 KB). B-frags read
// directly from fragment-ordered Wfrag (coalesced 16B/lane, L2-hot).
// 4 waves; wave wv owns output cols [32wv,32wv+32); acc[4 mtile][2 ntile].
// z written in SORTED row order (z_s). BN sums accumulate in registers
// across chunks; block computes scale/shift directly (no atomics, no
// separate stats kernel, no zeroed buffers).
// ---------------------------------------------------------------------------
__global__ __launch_bounds__(256, 4) void k_matvec(
    const int* __restrict__ order, const int* __restrict__ offsets,
    const int* __restrict__ nbr,
    const float* __restrict__ years, const float* __restrict__ months, const float* __restrict__ days,
    const float* __restrict__ ent,
    const float* __restrict__ yf, const float* __restrict__ yp, const float* __restrict__ ya,
    const float* __restrict__ mf, const float* __restrict__ mp, const float* __restrict__ ma,
    const float* __restrict__ df, const float* __restrict__ dp, const float* __restrict__ da,
    const unsigned short* __restrict__ Wfrag, const float* __restrict__ bias,
    const float* __restrict__ gamma, const float* __restrict__ beta,
    float* __restrict__ z_s, float* __restrict__ scale, float* __restrict__ shift)
{
    const int r     = blockIdx.x;
    const int start = offsets[r];
    const int cnt   = offsets[r + 1] - start;

    __shared__ __align__(16) unsigned short Xl[CHUNK * DIM];  // 16 KB
    __shared__ int s_ord[CHUNK];
    __shared__ int s_ni[CHUNK];

    const int t = threadIdx.x;
    const int wv = t >> 6;
    const int lane = t & 63;
    const int l15 = lane & 15;
    const int g = lane >> 4;

    const int nn0 = 32 * wv + l15;          // nt=0 column
    const int nn1 = 32 * wv + 16 + l15;     // nt=1 column
    const float bv0 = bias[r * DIM + nn0];
    const float bv1 = bias[r * DIM + nn1];

    float lsum0 = 0.f, lsq0 = 0.f, lsum1 = 0.f, lsq1 = 0.f;
    const unsigned short* Wr = Wfrag + (size_t)r * DIM * DIM;

    for (int cbase = 0; cbase < cnt; cbase += CHUNK) {
        const int mcnt = min(CHUNK, cnt - cbase);

        if (t < CHUNK) {
            int o = -1, ni = 0;
            if (t < mcnt) { o = order[start + cbase + t]; ni = nbr[o]; }
            s_ord[t] = o;
            s_ni[t]  = ni;
        }
        __syncthreads();

        // ---- gather X: 4 threads/row; entity 24 dims/thread, time 8/thread
        {
            const int m = t >> 2, s = t & 3;
            const int ni = s_ni[m];
            const bool vm = (m < mcnt);
            #pragma unroll
            for (int kk = 0; kk < 6; ++kk) {
                const int d = 4 * (s + 4 * kk);
                float4 e = *(const float4*)(ent + (size_t)ni * S_DIM + d);
                ushort4 b;
                b.x = vm ? f2bf(e.x) : 0; b.y = vm ? f2bf(e.y) : 0;
                b.z = vm ? f2bf(e.z) : 0; b.w = vm ? f2bf(e.w) : 0;
                *(ushort4*)&Xl[XIDX(m, d)] = b;
            }
            const int o = s_ord[m] < 0 ? 0 : s_ord[m];
            const float yr = years[o], mo = months[o], dy = days[o];
            #pragma unroll
            for (int hh = 0; hh < 2; ++hh) {
                const int j0 = s * 8 + hh * 4;
                const size_t tb = (size_t)ni * T_DIM + j0;
                const float4 vyf = *(const float4*)(yf + tb), vyp = *(const float4*)(yp + tb), vya = *(const float4*)(ya + tb);
                const float4 vmf = *(const float4*)(mf + tb), vmp = *(const float4*)(mp + tb), vma = *(const float4*)(ma + tb);
                const float4 vdf = *(const float4*)(df + tb), vdp = *(const float4*)(dp + tb), vda = *(const float4*)(da + tb);
                ushort4 b;
                #pragma unroll
                for (int j = 0; j < 4; ++j) {
                    const float fy = ((const float*)&vyf)[j] * yr + ((const float*)&vyp)[j];
                    const float fm = ((const float*)&vmf)[j] * mo + ((const float*)&vmp)[j];
                    const float fd = ((const float*)&vdf)[j] * dy + ((const float*)&vdp)[j];
                    float v = ((const float*)&vya)[j] * sinf(fy)
                            + ((const float*)&vma)[j] * sinf(fm)
                            + ((const float*)&vda)[j] * sinf(fd);
                    ((unsigned short*)&b)[j] = vm ? f2bf(v) : 0;
                }
                *(ushort4*)&Xl[XIDX(m, S_DIM + j0)] = b;
            }
        }
        __syncthreads();

        // ---- MFMA
        f32x4 acc[4][2];
        #pragma unroll
        for (int i = 0; i < 4; ++i)
            #pragma unroll
            for (int j = 0; j < 2; ++j) acc[i][j] = (f32x4)0.f;

        #pragma unroll
        for (int kk = 0; kk < 4; ++kk) {
            const int k0 = kk * 32;
            bf16x8 a[4];
            #pragma unroll
            for (int mt = 0; mt < 4; ++mt)
                a[mt] = *(const bf16x8*)&Xl[XIDX(16 * mt + l15, k0 + 8 * g)];
            const bf16x8 b0 = *(const bf16x8*)&Wr[(size_t)((kk * 4 + wv) * 2 + 0) * 512 + lane * 8];
            const bf16x8 b1 = *(const bf16x8*)&Wr[(size_t)((kk * 4 + wv) * 2 + 1) * 512 + lane * 8];
            #pragma unroll
            for (int mt = 0; mt < 4; ++mt) {
                acc[mt][0] = __builtin_amdgcn_mfma_f32_16x16x32_bf16(a[mt], b0, acc[mt][0], 0, 0, 0);
                acc[mt][1] = __builtin_amdgcn_mfma_f32_16x16x32_bf16(a[mt], b1, acc[mt][1], 0, 0, 0);
            }
        }

        // ---- epilogue: bias + z_s store + BN accumulate (registers)
        #pragma unroll
        for (int mt = 0; mt < 4; ++mt) {
            #pragma unroll
            for (int reg = 0; reg < 4; ++reg) {
                const int ml = 16 * mt + 4 * g + reg;
                if (ml < mcnt) {
                    const float v0 = acc[mt][0][reg] + bv0;
                    const float v1 = acc[mt][1][reg] + bv1;
                    const size_t row = (size_t)(start + cbase + ml) * DIM;
                    z_s[row + nn0] = v0;
                    z_s[row + nn1] = v1;
                    lsum0 += v0; lsq0 += v0 * v0;
                    lsum1 += v1; lsq1 += v1 * v1;
                }
            }
        }
        __syncthreads();   // Xl reads done before next chunk's gather
    }

    // ---- fold BN into affine scale/shift for this block's columns
    lsum0 += __shfl_xor(lsum0, 16); lsum0 += __shfl_xor(lsum0, 32);
    lsq0  += __shfl_xor(lsq0, 16);  lsq0  += __shfl_xor(lsq0, 32);
    lsum1 += __shfl_xor(lsum1, 16); lsum1 += __shfl_xor(lsum1, 32);
    lsq1  += __shfl_xor(lsq1, 16);  lsq1  += __shfl_xor(lsq1, 32);
    if (g == 0) {
        const float denom = (float)max(cnt, 1);
        #pragma unroll
        for (int nt = 0; nt < 2; ++nt) {
            const int i = r * DIM + (nt ? nn1 : nn0);
            const float s = nt ? lsum1 : lsum0;
            const float q = nt ? lsq1 : lsq0;
            float sc = 1.0f, sh = 0.0f;
            if (cnt > 1) {
                const float mean = s / denom;
                const float var  = fmaxf(q / denom - mean * mean, 0.0f);
                sc = gamma[i] * rsqrtf(var + BN_EPS);
                sh = beta[i] - mean * sc;
            }
            scale[i] = sc;
            shift[i] = sh;
        }
    }
}

// ---------------------------------------------------------------------------
// K4: atomic-free pooling: one block per query, edges pre-sorted by dst.
// ---------------------------------------------------------------------------
__global__ void k_pool2(const int* __restrict__ eorder, const int* __restrict__ dst_off,
                        const int* __restrict__ pool_src, const int* __restrict__ rel,
                        const int* __restrict__ rank,
                        const float* __restrict__ z_s,
                        const float* __restrict__ scale, const float* __restrict__ shift,
                        float* __restrict__ emb)
{
    const int q = blockIdx.x;
    const int d = threadIdx.x;
    const int e0 = dst_off[q], e1 = dst_off[q + 1];
    float acc = 0.f;
    for (int e = e0; e < e1; ++e) {
        const int s = pool_src[eorder[e]];
        const int r = rel[s];
        const int p = rank[s];
        const float v = z_s[(size_t)p * DIM + d] * scale[r * DIM + d] + shift[r * DIM + d];
        acc += fmaxf(v, 0.f);
    }
    emb[(size_t)q * DIM + d] = (e1 > e0) ? acc / (float)(e1 - e0) : 0.f;
}

// ---------------------------------------------------------------------------
// K5: TransE scoring
// ---------------------------------------------------------------------------
__global__ void k_score(const int* __restrict__ head, const int* __restrict__ tail,
                        const int* __restrict__ rels,
                        const float* __restrict__ emb, const float* __restrict__ rel_embs,
                        float* __restrict__ out)
{
    const int b = blockIdx.x;
    const int d = threadIdx.x;
    const int h = head[b], tq = tail[b], r = rels[b];

    const float diff = emb[(size_t)h * DIM + d] + rel_embs[r * DIM + d]
                     - emb[(size_t)tq * DIM + d];
    float sq = diff * diff;
    for (int off = 32; off > 0; off >>= 1) sq += __shfl_down(sq, off);
    __shared__ float partial[2];
    if ((threadIdx.x & 63) == 0) partial[threadIdx.x >> 6] = sq;
    __syncthreads();
    if (threadIdx.x == 0) out[b] = -sqrtf(partial[0] + partial[1]);
}

// ---------------------------------------------------------------------------
extern "C" void kernel_launch(void* const* d_in, const int* in_sizes, int n_in,
                              void* d_out, int out_size, void* d_ws, size_t ws_size,
                              hipStream_t stream) {
    const int*   neighbor_idx = (const int*)  d_in[0];
    const int*   rel_id       = (const int*)  d_in[1];
    const float* years        = (const float*)d_in[2];
    const float* months       = (const float*)d_in[3];
    const float* days         = (const float*)d_in[4];
    const int*   pool_src     = (const int*)  d_in[5];
    const int*   pool_dst     = (const int*)  d_in[6];
    const int*   head_pos     = (const int*)  d_in[7];
    const int*   tail_pos     = (const int*)  d_in[8];
    const int*   rels         = (const int*)  d_in[9];
    const float* ent_embs     = (const float*)d_in[10];
    const float* y_freq       = (const float*)d_in[11];
    const float* y_phi        = (const float*)d_in[12];
    const float* y_amp        = (const float*)d_in[13];
    const float* m_freq       = (const float*)d_in[14];
    const float* m_phi        = (const float*)d_in[15];
    const float* m_amp        = (const float*)d_in[16];
    const float* d_freq       = (const float*)d_in[17];
    const float* d_phi        = (const float*)d_in[18];
    const float* d_amp        = (const float*)d_in[19];
    const float* rel_embs     = (const float*)d_in[20];
    const float* W            = (const float*)d_in[21];
    const float* bias         = (const float*)d_in[22];
    const float* gamma        = (const float*)d_in[23];
    const float* beta         = (const float*)d_in[24];

    float* out = (float*)d_out;

    // workspace layout (float units). No pre-zeroing required anywhere.
    float* ws = (float*)d_ws;
    size_t off = 0;
    unsigned short* Wfrag = (unsigned short*)(ws + off); off += (size_t)R2 * DIM * DIM / 2;  // 15 MB
    float* z_s   = ws + off; off += (size_t)N_NBR * DIM;   // 16 MB
    float* scale = ws + off; off += (size_t)R2 * DIM;
    float* shift = ws + off; off += (size_t)R2 * DIM;
    float* emb   = ws + off; off += (size_t)Q_ENT * DIM;
    int* offsets  = (int*)(ws + off); off += R2 + 1;
    int* cur_rel  = (int*)(ws + off); off += R2;
    int* dst_off  = (int*)(ws + off); off += Q_ENT + 1;
    int* cur_dst  = (int*)(ws + off); off += Q_ENT;
    int* order    = (int*)(ws + off); off += N_NBR;
    int* rank     = (int*)(ws + off); off += N_NBR;
    int* eorder   = (int*)(ws + off); off += E_EDGE;

    k_front<<<R2 + 2, 256, 0, stream>>>(W, Wfrag, rel_id, pool_dst,
                                        offsets, cur_rel, dst_off, cur_dst);

    k_scatter<<<(N_NBR + 255) / 256, 256, 0, stream>>>(rel_id, cur_rel, order, rank,
                                                       pool_dst, cur_dst, eorder);

    k_matvec<<<R2, 256, 0, stream>>>(order, offsets, neighbor_idx,
                                     years, months, days, ent_embs,
                                     y_freq, y_phi, y_amp,
                                     m_freq, m_phi, m_amp,
                                     d_freq, d_phi, d_amp,
                                     Wfrag, bias, gamma, beta,
                                     z_s, scale, shift);

    k_pool2<<<Q_ENT, DIM, 0, stream>>>(eorder, dst_off, pool_src, rel_id, rank,
                                       z_s, scale, shift, emb);

    k_score<<<B_TRI, DIM, 0, stream>>>(head_pos, tail_pos, rels, emb, rel_embs, out);
}

// Round 8
// 83.625 us; speedup vs baseline: 1.2438x; 1.2438x over previous
//
#include <hip/hip_runtime.h>
#include <math.h>

#define NUM_ENT 10000
#define NUM_REL 230
#define R2      460
#define S_DIM   96
#define T_DIM   32
#define DIM     128
#define N_NBR   32768
#define Q_ENT   4096
#define E_EDGE  32768
#define B_TRI   1024
#define BN_EPS  1e-5f
#define CHUNK   64

typedef __attribute__((ext_vector_type(8))) short bf16x8;
typedef __attribute__((ext_vector_type(4))) float f32x4;

// f32 -> bf16 round-to-nearest-even
__device__ __forceinline__ unsigned short f2bf(float f) {
    unsigned int u = __float_as_uint(f);
    u = (u + 0x7FFFu + ((u >> 16) & 1u)) >> 16;
    return (unsigned short)u;
}

// X LDS swizzle (ushort units): breaks the 256B row stride for A-frag b128
// reads. XOR bits >=3 keep 4-ushort groups contiguous (8B stores ok).
__device__ __forceinline__ int XIDX(int m, int d) {
    return (m * DIM + d) ^ ((m & 7) << 3);
}

// ---------------------------------------------------------------------------
// K0: zero hist_rel(460)+hist_dst(4096) = 4556 ints (1139 int4)
// ---------------------------------------------------------------------------
__global__ void k_zero(int* __restrict__ p, int n4) {
    int i = blockIdx.x * blockDim.x + threadIdx.x;
    if (i < n4) ((int4*)p)[i] = make_int4(0, 0, 0, 0);
}

// ---------------------------------------------------------------------------
// K1: blocks [0,460): W[r] f32 -> bf16 in per-lane MFMA fragment order.
//   Wfrag ushort offset: ((kk*4+wv)*2+h)*512 + lane*8 + j holds
//   bf16(W[r][32*kk + 8*(lane>>4) + j][32*wv + 16*h + (lane&15)]).
// blocks [460,588): PARALLEL histograms (global atomics into zeroed bufs).
// ---------------------------------------------------------------------------
__global__ __launch_bounds__(256, 2) void k_front(
    const float* __restrict__ W, unsigned short* __restrict__ Wfrag,
    const int* __restrict__ rel, const int* __restrict__ pdst,
    int* __restrict__ hist_rel, int* __restrict__ hist_dst)
{
    const int t = threadIdx.x;
    if (blockIdx.x >= R2) {
        const int i = (blockIdx.x - R2) * 256 + t;
        if (i < N_NBR) atomicAdd(&hist_rel[rel[i]], 1);
        if (i < E_EDGE) atomicAdd(&hist_dst[pdst[i]], 1);
        return;
    }
    const int r = blockIdx.x;
    __shared__ float Wl[DIM * DIM];   // 64 KB
    {
        const float4* Wg = (const float4*)(W + (size_t)r * DIM * DIM);
        float4* Wl4 = (float4*)Wl;
        #pragma unroll
        for (int i = 0; i < 16; ++i)
            Wl4[t + i * 256] = Wg[t + i * 256];
    }
    __syncthreads();
    unsigned short* dst = Wfrag + (size_t)r * DIM * DIM;
    #pragma unroll
    for (int it = 0; it < 8; ++it) {
        const int id = t + it * 256;            // 0..2047
        const int lane = id & 63;
        const int h    = (id >> 6) & 1;
        const int wv   = (id >> 7) & 3;
        const int kk   = (id >> 9) & 3;
        const int n  = 32 * wv + 16 * h + (lane & 15);
        const int kb = 32 * kk + 8 * (lane >> 4);
        ushort4 lo, hi;
        lo.x = f2bf(Wl[(kb + 0) * DIM + n]);
        lo.y = f2bf(Wl[(kb + 1) * DIM + n]);
        lo.z = f2bf(Wl[(kb + 2) * DIM + n]);
        lo.w = f2bf(Wl[(kb + 3) * DIM + n]);
        hi.x = f2bf(Wl[(kb + 4) * DIM + n]);
        hi.y = f2bf(Wl[(kb + 5) * DIM + n]);
        hi.z = f2bf(Wl[(kb + 6) * DIM + n]);
        hi.w = f2bf(Wl[(kb + 7) * DIM + n]);
        *(ushort4*)&dst[id * 8]     = lo;
        *(ushort4*)&dst[id * 8 + 4] = hi;
    }
}

// ---------------------------------------------------------------------------
// K2: fused scans (2 blocks x 1024 thr). Block 0: rel hist -> offsets[461],
// cursor init cur_rel. Block 1: dst hist -> dst_off[4097], cursor cur_dst.
// ---------------------------------------------------------------------------
__global__ void k_scan_both(const int* __restrict__ hist_rel, int* __restrict__ offsets,
                            int* __restrict__ cur_rel,
                            const int* __restrict__ hist_dst, int* __restrict__ dst_off,
                            int* __restrict__ cur_dst)
{
    __shared__ int s[1024];
    const int t = threadIdx.x;
    if (blockIdx.x == 0) {
        const int h = (t < R2) ? hist_rel[t] : 0;
        if (t < 512) s[t] = h;
        __syncthreads();
        for (int off = 1; off < 512; off <<= 1) {
            int a = (t >= off && t < 512) ? s[t - off] : 0;
            __syncthreads();
            if (t < 512) s[t] += a;
            __syncthreads();
        }
        if (t == 0) offsets[0] = 0;
        if (t < R2) {
            offsets[t + 1] = s[t];      // inclusive
            cur_rel[t] = s[t] - h;      // exclusive
        }
    } else {
        const int base = t * 4;
        int v0 = hist_dst[base], v1 = hist_dst[base + 1];
        int v2 = hist_dst[base + 2], v3 = hist_dst[base + 3];
        s[t] = v0 + v1 + v2 + v3;
        __syncthreads();
        for (int off = 1; off < 1024; off <<= 1) {
            int a = (t >= off) ? s[t - off] : 0;
            __syncthreads();
            s[t] += a;
            __syncthreads();
        }
        int run = (t > 0) ? s[t - 1] : 0;
        dst_off[base] = run; cur_dst[base] = run; run += v0;
        dst_off[base + 1] = run; cur_dst[base + 1] = run; run += v1;
        dst_off[base + 2] = run; cur_dst[base + 2] = run; run += v2;
        dst_off[base + 3] = run; cur_dst[base + 3] = run; run += v3;
        if (t == 1023) dst_off[4096] = run;
    }
}

// ---------------------------------------------------------------------------
// K3: scatter: rel-sorted neighbor order (+rank) and dst-sorted edge order.
// Cursors pre-initialized by k_scan_both.
// ---------------------------------------------------------------------------
__global__ void k_scatter(const int* __restrict__ rel,
                          int* __restrict__ cur_rel, int* __restrict__ order,
                          int* __restrict__ rank,
                          const int* __restrict__ pdst,
                          int* __restrict__ cur_dst, int* __restrict__ eorder) {
    int i = blockIdx.x * blockDim.x + threadIdx.x;
    if (i < N_NBR) {
        const int pos = atomicAdd(&cur_rel[rel[i]], 1);
        order[pos] = i;
        rank[i] = pos;
    }
    if (i < E_EDGE) {
        eorder[atomicAdd(&cur_dst[pdst[i]], 1)] = i;
    }
}

// ---------------------------------------------------------------------------
// K4: MFMA matvec. ONE BLOCK (512 thr = 8 waves) PER RELATION; the 8 waves
// process TWO 64-row chunks concurrently (half = wid>>2). X gathered as bf16
// into swizzled LDS [2][64][128] (32 KB). B-frags read from fragment-ordered
// Wfrag (coalesced 16B/lane, L2-hot). BN stats accumulate in registers,
// cross-half combine via LDS; block then applies BN affine + ReLU IN PLACE
// to its z_s rows (scale/shift never leave the block).
// ---------------------------------------------------------------------------
__global__ __launch_bounds__(512, 4) void k_matvec(
    const int* __restrict__ order, const int* __restrict__ offsets,
    const int* __restrict__ nbr,
    const float* __restrict__ years, const float* __restrict__ months, const float* __restrict__ days,
    const float* __restrict__ ent,
    const float* __restrict__ yf, const float* __restrict__ yp, const float* __restrict__ ya,
    const float* __restrict__ mf, const float* __restrict__ mp, const float* __restrict__ ma,
    const float* __restrict__ df, const float* __restrict__ dp, const float* __restrict__ da,
    const unsigned short* __restrict__ Wfrag, const float* __restrict__ bias,
    const float* __restrict__ gamma, const float* __restrict__ beta,
    float* __restrict__ z_s)
{
    const int r     = blockIdx.x;
    const int start = offsets[r];
    const int cnt   = offsets[r + 1] - start;

    __shared__ __align__(16) unsigned short Xl[2][CHUNK * DIM];  // 32 KB
    __shared__ int s_ord[2][CHUNK];
    __shared__ int s_ni[2][CHUNK];
    __shared__ float bnred[8][2][16][2];   // [wid][nt][l15][sum|sq]
    __shared__ float scl[DIM], shf[DIM];

    const int t    = threadIdx.x;
    const int wid  = t >> 6;        // 0..7
    const int half = wid >> 2;      // 0,1 : which chunk of the pair
    const int wv   = wid & 3;       // column group
    const int lane = t & 63;
    const int l15  = lane & 15;
    const int g    = lane >> 4;

    const int nn0 = 32 * wv + l15;
    const int nn1 = nn0 + 16;
    const float bv0 = bias[r * DIM + nn0];
    const float bv1 = bias[r * DIM + nn1];

    float lsum0 = 0.f, lsq0 = 0.f, lsum1 = 0.f, lsq1 = 0.f;
    const unsigned short* Wr = Wfrag + (size_t)r * DIM * DIM;

    for (int cbase = 0; cbase < cnt; cbase += 2 * CHUNK) {
        const int hbase = cbase + half * CHUNK;
        const int mcnt  = min(CHUNK, max(0, cnt - hbase));

        if (t < 2 * CHUNK) {
            const int hh = t >> 6;   // half being staged
            const int m  = t & 63;
            const int gb = cbase + hh * CHUNK;
            int o = -1, ni = 0;
            if (gb + m < cnt) { o = order[start + gb + m]; ni = nbr[o]; }
            s_ord[hh][m] = o;
            s_ni[hh][m]  = ni;
        }
        __syncthreads();

        // ---- gather X for this half (256 threads): 4 thr/row
        if (mcnt > 0) {
            const int lt = t & 255;
            const int m = lt >> 2, s = lt & 3;
            const int ni = s_ni[half][m];
            const bool vm = (m < mcnt);
            #pragma unroll
            for (int kk = 0; kk < 6; ++kk) {
                const int d = 4 * (s + 4 * kk);
                float4 e = *(const float4*)(ent + (size_t)ni * S_DIM + d);
                ushort4 b;
                b.x = vm ? f2bf(e.x) : 0; b.y = vm ? f2bf(e.y) : 0;
                b.z = vm ? f2bf(e.z) : 0; b.w = vm ? f2bf(e.w) : 0;
                *(ushort4*)&Xl[half][XIDX(m, d)] = b;
            }
            const int o = s_ord[half][m] < 0 ? 0 : s_ord[half][m];
            const float yr = years[o], mo = months[o], dy = days[o];
            #pragma unroll
            for (int hh = 0; hh < 2; ++hh) {
                const int j0 = s * 8 + hh * 4;
                const size_t tb = (size_t)ni * T_DIM + j0;
                const float4 vyf = *(const float4*)(yf + tb), vyp = *(const float4*)(yp + tb), vya = *(const float4*)(ya + tb);
                const float4 vmf = *(const float4*)(mf + tb), vmp = *(const float4*)(mp + tb), vma = *(const float4*)(ma + tb);
                const float4 vdf = *(const float4*)(df + tb), vdp = *(const float4*)(dp + tb), vda = *(const float4*)(da + tb);
                ushort4 b;
                #pragma unroll
                for (int j = 0; j < 4; ++j) {
                    const float fy = ((const float*)&vyf)[j] * yr + ((const float*)&vyp)[j];
                    const float fm = ((const float*)&vmf)[j] * mo + ((const float*)&vmp)[j];
                    const float fd = ((const float*)&vdf)[j] * dy + ((const float*)&vdp)[j];
                    float v = ((const float*)&vya)[j] * sinf(fy)
                            + ((const float*)&vma)[j] * sinf(fm)
                            + ((const float*)&vda)[j] * sinf(fd);
                    ((unsigned short*)&b)[j] = vm ? f2bf(v) : 0;
                }
                *(ushort4*)&Xl[half][XIDX(m, S_DIM + j0)] = b;
            }
        }
        __syncthreads();

        // ---- MFMA + epilogue for this half
        if (mcnt > 0) {
            f32x4 acc[4][2];
            #pragma unroll
            for (int i = 0; i < 4; ++i)
                #pragma unroll
                for (int j = 0; j < 2; ++j) acc[i][j] = (f32x4)0.f;

            #pragma unroll
            for (int kk = 0; kk < 4; ++kk) {
                const int k0 = kk * 32;
                bf16x8 a[4];
                #pragma unroll
                for (int mt = 0; mt < 4; ++mt)
                    a[mt] = *(const bf16x8*)&Xl[half][XIDX(16 * mt + l15, k0 + 8 * g)];
                const bf16x8 b0 = *(const bf16x8*)&Wr[(size_t)((kk * 4 + wv) * 2 + 0) * 512 + lane * 8];
                const bf16x8 b1 = *(const bf16x8*)&Wr[(size_t)((kk * 4 + wv) * 2 + 1) * 512 + lane * 8];
                #pragma unroll
                for (int mt = 0; mt < 4; ++mt) {
                    acc[mt][0] = __builtin_amdgcn_mfma_f32_16x16x32_bf16(a[mt], b0, acc[mt][0], 0, 0, 0);
                    acc[mt][1] = __builtin_amdgcn_mfma_f32_16x16x32_bf16(a[mt], b1, acc[mt][1], 0, 0, 0);
                }
            }

            #pragma unroll
            for (int mt = 0; mt < 4; ++mt) {
                #pragma unroll
                for (int reg = 0; reg < 4; ++reg) {
                    const int ml = 16 * mt + 4 * g + reg;
                    if (ml < mcnt) {
                        const float v0 = acc[mt][0][reg] + bv0;
                        const float v1 = acc[mt][1][reg] + bv1;
                        const size_t row = (size_t)(start + hbase + ml) * DIM;
                        z_s[row + nn0] = v0;
                        z_s[row + nn1] = v1;
                        lsum0 += v0; lsq0 += v0 * v0;
                        lsum1 += v1; lsq1 += v1 * v1;
                    }
                }
            }
        }
        __syncthreads();
    }

    // ---- BN fold: intra-wave (over g), then cross-half via LDS
    lsum0 += __shfl_xor(lsum0, 16); lsum0 += __shfl_xor(lsum0, 32);
    lsq0  += __shfl_xor(lsq0, 16);  lsq0  += __shfl_xor(lsq0, 32);
    lsum1 += __shfl_xor(lsum1, 16); lsum1 += __shfl_xor(lsum1, 32);
    lsq1  += __shfl_xor(lsq1, 16);  lsq1  += __shfl_xor(lsq1, 32);
    if (g == 0) {
        bnred[wid][0][l15][0] = lsum0; bnred[wid][0][l15][1] = lsq0;
        bnred[wid][1][l15][0] = lsum1; bnred[wid][1][l15][1] = lsq1;
    }
    __syncthreads();
    if (half == 0 && g == 0) {
        #pragma unroll
        for (int nt = 0; nt < 2; ++nt) {
            const int col = 32 * wv + 16 * nt + l15;
            const float s = bnred[wid][nt][l15][0] + bnred[wid + 4][nt][l15][0];
            const float q = bnred[wid][nt][l15][1] + bnred[wid + 4][nt][l15][1];
            float sc = 1.f, sh = 0.f;
            if (cnt > 1) {
                const float mean = s / (float)cnt;
                const float var  = fmaxf(q / (float)cnt - mean * mean, 0.f);
                const int gi = r * DIM + col;
                sc = gamma[gi] * rsqrtf(var + BN_EPS);
                sh = beta[gi] - mean * sc;
            }
            scl[col] = sc; shf[col] = sh;
        }
    }
    __threadfence_block();
    __syncthreads();

    // ---- apply BN affine + ReLU in place (rows L2-hot)
    const int col = t & 127;
    const int rs  = t >> 7;   // 0..3
    const float sc = scl[col], sh = shf[col];
    for (int i = rs; i < cnt; i += 4) {
        const size_t idx = (size_t)(start + i) * DIM + col;
        z_s[idx] = fmaxf(z_s[idx] * sc + sh, 0.f);
    }
}

// ---------------------------------------------------------------------------
// K5: atomic-free pooling: one block per query; z_s already BN+ReLU'd.
// ---------------------------------------------------------------------------
__global__ void k_pool2(const int* __restrict__ eorder, const int* __restrict__ dst_off,
                        const int* __restrict__ pool_src, const int* __restrict__ rank,
                        const float* __restrict__ z_s, float* __restrict__ emb)
{
    const int q = blockIdx.x;
    const int d = threadIdx.x;
    const int e0 = dst_off[q], e1 = dst_off[q + 1];
    float acc = 0.f;
    for (int e = e0; e < e1; ++e) {
        const int p = rank[pool_src[eorder[e]]];
        acc += z_s[(size_t)p * DIM + d];
    }
    emb[(size_t)q * DIM + d] = (e1 > e0) ? acc / (float)(e1 - e0) : 0.f;
}

// ---------------------------------------------------------------------------
// K6: TransE scoring
// ---------------------------------------------------------------------------
__global__ void k_score(const int* __restrict__ head, const int* __restrict__ tail,
                        const int* __restrict__ rels,
                        const float* __restrict__ emb, const float* __restrict__ rel_embs,
                        float* __restrict__ out)
{
    const int b = blockIdx.x;
    const int d = threadIdx.x;
    const int h = head[b], tq = tail[b], r = rels[b];

    const float diff = emb[(size_t)h * DIM + d] + rel_embs[r * DIM + d]
                     - emb[(size_t)tq * DIM + d];
    float sq = diff * diff;
    for (int off = 32; off > 0; off >>= 1) sq += __shfl_down(sq, off);
    __shared__ float partial[2];
    if ((threadIdx.x & 63) == 0) partial[threadIdx.x >> 6] = sq;
    __syncthreads();
    if (threadIdx.x == 0) out[b] = -sqrtf(partial[0] + partial[1]);
}

// ---------------------------------------------------------------------------
extern "C" void kernel_launch(void* const* d_in, const int* in_sizes, int n_in,
                              void* d_out, int out_size, void* d_ws, size_t ws_size,
                              hipStream_t stream) {
    const int*   neighbor_idx = (const int*)  d_in[0];
    const int*   rel_id       = (const int*)  d_in[1];
    const float* years        = (const float*)d_in[2];
    const float* months       = (const float*)d_in[3];
    const float* days         = (const float*)d_in[4];
    const int*   pool_src     = (const int*)  d_in[5];
    const int*   pool_dst     = (const int*)  d_in[6];
    const int*   head_pos     = (const int*)  d_in[7];
    const int*   tail_pos     = (const int*)  d_in[8];
    const int*   rels         = (const int*)  d_in[9];
    const float* ent_embs     = (const float*)d_in[10];
    const float* y_freq       = (const float*)d_in[11];
    const float* y_phi        = (const float*)d_in[12];
    const float* y_amp        = (const float*)d_in[13];
    const float* m_freq       = (const float*)d_in[14];
    const float* m_phi        = (const float*)d_in[15];
    const float* m_amp        = (const float*)d_in[16];
    const float* d_freq       = (const float*)d_in[17];
    const float* d_phi        = (const float*)d_in[18];
    const float* d_amp        = (const float*)d_in[19];
    const float* rel_embs     = (const float*)d_in[20];
    const float* W            = (const float*)d_in[21];
    const float* bias         = (const float*)d_in[22];
    const float* gamma        = (const float*)d_in[23];
    const float* beta         = (const float*)d_in[24];

    float* out = (float*)d_out;

    // workspace layout (float units)
    float* ws = (float*)d_ws;
    size_t off = 0;
    unsigned short* Wfrag = (unsigned short*)(ws + off); off += (size_t)R2 * DIM * DIM / 2;  // 15 MB
    float* z_s = ws + off; off += (size_t)N_NBR * DIM;   // 16 MB
    float* emb = ws + off; off += (size_t)Q_ENT * DIM;
    int* hist_rel = (int*)(ws + off); off += R2;       // zero region (4556 ints)
    int* hist_dst = (int*)(ws + off); off += Q_ENT;
    int* offsets  = (int*)(ws + off); off += R2 + 1;
    int* cur_rel  = (int*)(ws + off); off += R2;
    int* dst_off  = (int*)(ws + off); off += Q_ENT + 1;
    int* cur_dst  = (int*)(ws + off); off += Q_ENT;
    int* order    = (int*)(ws + off); off += N_NBR;
    int* rank     = (int*)(ws + off); off += N_NBR;
    int* eorder   = (int*)(ws + off); off += E_EDGE;

    const int nzero4 = (R2 + Q_ENT + 3) / 4;   // 1139 int4
    k_zero<<<(nzero4 + 255) / 256, 256, 0, stream>>>(hist_rel, nzero4);

    k_front<<<R2 + (N_NBR + 255) / 256, 256, 0, stream>>>(
        W, Wfrag, rel_id, pool_dst, hist_rel, hist_dst);

    k_scan_both<<<2, 1024, 0, stream>>>(hist_rel, offsets, cur_rel,
                                        hist_dst, dst_off, cur_dst);

    k_scatter<<<(N_NBR + 255) / 256, 256, 0, stream>>>(rel_id, cur_rel, order, rank,
                                                       pool_dst, cur_dst, eorder);

    k_matvec<<<R2, 512, 0, stream>>>(order, offsets, neighbor_idx,
                                     years, months, days, ent_embs,
                                     y_freq, y_phi, y_amp,
                                     m_freq, m_phi, m_amp,
                                     d_freq, d_phi, d_amp,
                                     Wfrag, bias, gamma, beta, z_s);

    k_pool2<<<Q_ENT, DIM, 0, stream>>>(eorder, dst_off, pool_src, rank, z_s, emb);

    k_score<<<B_TRI, DIM, 0, stream>>>(head_pos, tail_pos, rels, emb, rel_embs, out);
}

// Round 9
// 76.752 us; speedup vs baseline: 1.3551x; 1.0895x over previous
//
#include <hip/hip_runtime.h>
#include <math.h>

#define NUM_ENT 10000
#define NUM_REL 230
#define R2      460
#define S_DIM   96
#define T_DIM   32
#define DIM     128
#define N_NBR   32768
#define Q_ENT   4096
#define E_EDGE  32768
#define B_TRI   1024
#define BN_EPS  1e-5f
#define CHUNK   64

typedef __attribute__((ext_vector_type(8))) short bf16x8;
typedef __attribute__((ext_vector_type(4))) float f32x4;

// f32 -> bf16 round-to-nearest-even
__device__ __forceinline__ unsigned short f2bf(float f) {
    unsigned int u = __float_as_uint(f);
    u = (u + 0x7FFFu + ((u >> 16) & 1u)) >> 16;
    return (unsigned short)u;
}

// X LDS swizzle (ushort units): breaks the 256B row stride for A-frag b128
// reads. XOR bits >=3 keep 4-ushort groups contiguous (8B stores ok).
__device__ __forceinline__ int XIDX(int m, int d) {
    return (m * DIM + d) ^ ((m & 7) << 3);
}

// ---------------------------------------------------------------------------
// K0: zero hist_rel(460)+hist_dst(4096) = 4556 ints (1139 int4)
// ---------------------------------------------------------------------------
__global__ void k_zero(int* __restrict__ p, int n4) {
    int i = blockIdx.x * blockDim.x + threadIdx.x;
    if (i < n4) ((int4*)p)[i] = make_int4(0, 0, 0, 0);
}

// ---------------------------------------------------------------------------
// K1: blocks [0,460): W[r] f32 -> bf16 in per-lane MFMA fragment order.
//   Wfrag ushort offset: ((kk*4+wv)*2+h)*512 + lane*8 + j holds
//   bf16(W[r][32*kk + 8*(lane>>4) + j][32*wv + 16*h + (lane&15)]).
// blocks [460,588): PARALLEL histograms (global atomics into zeroed bufs).
// ---------------------------------------------------------------------------
__global__ __launch_bounds__(256, 2) void k_front(
    const float* __restrict__ W, unsigned short* __restrict__ Wfrag,
    const int* __restrict__ rel, const int* __restrict__ pdst,
    int* __restrict__ hist_rel, int* __restrict__ hist_dst)
{
    const int t = threadIdx.x;
    if (blockIdx.x >= R2) {
        const int i = (blockIdx.x - R2) * 256 + t;
        if (i < N_NBR) atomicAdd(&hist_rel[rel[i]], 1);
        if (i < E_EDGE) atomicAdd(&hist_dst[pdst[i]], 1);
        return;
    }
    const int r = blockIdx.x;
    __shared__ float Wl[DIM * DIM];   // 64 KB
    {
        const float4* Wg = (const float4*)(W + (size_t)r * DIM * DIM);
        float4* Wl4 = (float4*)Wl;
        #pragma unroll
        for (int i = 0; i < 16; ++i)
            Wl4[t + i * 256] = Wg[t + i * 256];
    }
    __syncthreads();
    unsigned short* dst = Wfrag + (size_t)r * DIM * DIM;
    #pragma unroll
    for (int it = 0; it < 8; ++it) {
        const int id = t + it * 256;            // 0..2047
        const int lane = id & 63;
        const int h    = (id >> 6) & 1;
        const int wv   = (id >> 7) & 3;
        const int kk   = (id >> 9) & 3;
        const int n  = 32 * wv + 16 * h + (lane & 15);
        const int kb = 32 * kk + 8 * (lane >> 4);
        ushort4 lo, hi;
        lo.x = f2bf(Wl[(kb + 0) * DIM + n]);
        lo.y = f2bf(Wl[(kb + 1) * DIM + n]);
        lo.z = f2bf(Wl[(kb + 2) * DIM + n]);
        lo.w = f2bf(Wl[(kb + 3) * DIM + n]);
        hi.x = f2bf(Wl[(kb + 4) * DIM + n]);
        hi.y = f2bf(Wl[(kb + 5) * DIM + n]);
        hi.z = f2bf(Wl[(kb + 6) * DIM + n]);
        hi.w = f2bf(Wl[(kb + 7) * DIM + n]);
        *(ushort4*)&dst[id * 8]     = lo;
        *(ushort4*)&dst[id * 8 + 4] = hi;
    }
}

// ---------------------------------------------------------------------------
// K2: fused scans (2 blocks x 1024 thr). Block 0: rel hist -> offsets[461],
// cursor init cur_rel. Block 1: dst hist -> dst_off[4097], cursor cur_dst.
// ---------------------------------------------------------------------------
__global__ void k_scan_both(const int* __restrict__ hist_rel, int* __restrict__ offsets,
                            int* __restrict__ cur_rel,
                            const int* __restrict__ hist_dst, int* __restrict__ dst_off,
                            int* __restrict__ cur_dst)
{
    __shared__ int s[1024];
    const int t = threadIdx.x;
    if (blockIdx.x == 0) {
        const int h = (t < R2) ? hist_rel[t] : 0;
        if (t < 512) s[t] = h;
        __syncthreads();
        for (int off = 1; off < 512; off <<= 1) {
            int a = (t >= off && t < 512) ? s[t - off] : 0;
            __syncthreads();
            if (t < 512) s[t] += a;
            __syncthreads();
        }
        if (t == 0) offsets[0] = 0;
        if (t < R2) {
            offsets[t + 1] = s[t];      // inclusive
            cur_rel[t] = s[t] - h;      // exclusive
        }
    } else {
        const int base = t * 4;
        int v0 = hist_dst[base], v1 = hist_dst[base + 1];
        int v2 = hist_dst[base + 2], v3 = hist_dst[base + 3];
        s[t] = v0 + v1 + v2 + v3;
        __syncthreads();
        for (int off = 1; off < 1024; off <<= 1) {
            int a = (t >= off) ? s[t - off] : 0;
            __syncthreads();
            s[t] += a;
            __syncthreads();
        }
        int run = (t > 0) ? s[t - 1] : 0;
        dst_off[base] = run; cur_dst[base] = run; run += v0;
        dst_off[base + 1] = run; cur_dst[base + 1] = run; run += v1;
        dst_off[base + 2] = run; cur_dst[base + 2] = run; run += v2;
        dst_off[base + 3] = run; cur_dst[base + 3] = run; run += v3;
        if (t == 1023) dst_off[4096] = run;
    }
}

// ---------------------------------------------------------------------------
// K3: scatter. rel-sorted neighbor order; rankpack[i] = row | (rel<<17);
// dst-sorted edge list stores the SOURCE NEIGHBOR ID directly (one less
// indirection in pooling).
// ---------------------------------------------------------------------------
__global__ void k_scatter(const int* __restrict__ rel,
                          int* __restrict__ cur_rel, int* __restrict__ order,
                          int* __restrict__ rankpack,
                          const int* __restrict__ psrc, const int* __restrict__ pdst,
                          int* __restrict__ cur_dst, int* __restrict__ eorder_src) {
    int i = blockIdx.x * blockDim.x + threadIdx.x;
    if (i < N_NBR) {
        const int r = rel[i];
        const int pos = atomicAdd(&cur_rel[r], 1);
        order[pos] = i;
        rankpack[i] = pos | (r << 17);
    }
    if (i < E_EDGE) {
        eorder_src[atomicAdd(&cur_dst[pdst[i]], 1)] = psrc[i];
    }
}

// ---------------------------------------------------------------------------
// K4: MFMA matvec. ONE BLOCK (512 thr = 8 waves) PER RELATION; the 8 waves
// process TWO 64-row chunks concurrently (half = wid>>2). X gathered as bf16
// into swizzled LDS [2][64][128] (32 KB). B-frags read from fragment-ordered
// Wfrag (coalesced 16B/lane, L2-hot). BN stats accumulate in registers,
// cross-half combine via LDS; block emits per-(rel,col) scale/shift to
// global (applied later in pooling — z_s stays raw, no rewrite pass).
// ---------------------------------------------------------------------------
__global__ __launch_bounds__(512, 4) void k_matvec(
    const int* __restrict__ order, const int* __restrict__ offsets,
    const int* __restrict__ nbr,
    const float* __restrict__ years, const float* __restrict__ months, const float* __restrict__ days,
    const float* __restrict__ ent,
    const float* __restrict__ yf, const float* __restrict__ yp, const float* __restrict__ ya,
    const float* __restrict__ mf, const float* __restrict__ mp, const float* __restrict__ ma,
    const float* __restrict__ df, const float* __restrict__ dp, const float* __restrict__ da,
    const unsigned short* __restrict__ Wfrag, const float* __restrict__ bias,
    const float* __restrict__ gamma, const float* __restrict__ beta,
    float* __restrict__ z_s, float* __restrict__ scale, float* __restrict__ shift)
{
    const int r     = blockIdx.x;
    const int start = offsets[r];
    const int cnt   = offsets[r + 1] - start;

    __shared__ __align__(16) unsigned short Xl[2][CHUNK * DIM];  // 32 KB
    __shared__ int s_ord[2][CHUNK];
    __shared__ int s_ni[2][CHUNK];
    __shared__ float bnred[8][2][16][2];   // [wid][nt][l15][sum|sq]

    const int t    = threadIdx.x;
    const int wid  = t >> 6;        // 0..7
    const int half = wid >> 2;      // 0,1 : which chunk of the pair
    const int wv   = wid & 3;       // column group
    const int lane = t & 63;
    const int l15  = lane & 15;
    const int g    = lane >> 4;

    const int nn0 = 32 * wv + l15;
    const int nn1 = nn0 + 16;
    const float bv0 = bias[r * DIM + nn0];
    const float bv1 = bias[r * DIM + nn1];

    float lsum0 = 0.f, lsq0 = 0.f, lsum1 = 0.f, lsq1 = 0.f;
    const unsigned short* Wr = Wfrag + (size_t)r * DIM * DIM;

    for (int cbase = 0; cbase < cnt; cbase += 2 * CHUNK) {
        const int hbase = cbase + half * CHUNK;
        const int mcnt  = min(CHUNK, max(0, cnt - hbase));

        if (t < 2 * CHUNK) {
            const int hh = t >> 6;   // half being staged
            const int m  = t & 63;
            const int gb = cbase + hh * CHUNK;
            int o = -1, ni = 0;
            if (gb + m < cnt) { o = order[start + gb + m]; ni = nbr[o]; }
            s_ord[hh][m] = o;
            s_ni[hh][m]  = ni;
        }
        __syncthreads();

        // ---- gather X for this half (256 threads): 4 thr/row
        if (mcnt > 0) {
            const int lt = t & 255;
            const int m = lt >> 2, s = lt & 3;
            const int ni = s_ni[half][m];
            const bool vm = (m < mcnt);
            #pragma unroll
            for (int kk = 0; kk < 6; ++kk) {
                const int d = 4 * (s + 4 * kk);
                float4 e = *(const float4*)(ent + (size_t)ni * S_DIM + d);
                ushort4 b;
                b.x = vm ? f2bf(e.x) : 0; b.y = vm ? f2bf(e.y) : 0;
                b.z = vm ? f2bf(e.z) : 0; b.w = vm ? f2bf(e.w) : 0;
                *(ushort4*)&Xl[half][XIDX(m, d)] = b;
            }
            const int o = s_ord[half][m] < 0 ? 0 : s_ord[half][m];
            const float yr = years[o], mo = months[o], dy = days[o];
            #pragma unroll
            for (int hh = 0; hh < 2; ++hh) {
                const int j0 = s * 8 + hh * 4;
                const size_t tb = (size_t)ni * T_DIM + j0;
                const float4 vyf = *(const float4*)(yf + tb), vyp = *(const float4*)(yp + tb), vya = *(const float4*)(ya + tb);
                const float4 vmf = *(const float4*)(mf + tb), vmp = *(const float4*)(mp + tb), vma = *(const float4*)(ma + tb);
                const float4 vdf = *(const float4*)(df + tb), vdp = *(const float4*)(dp + tb), vda = *(const float4*)(da + tb);
                ushort4 b;
                #pragma unroll
                for (int j = 0; j < 4; ++j) {
                    const float fy = ((const float*)&vyf)[j] * yr + ((const float*)&vyp)[j];
                    const float fm = ((const float*)&vmf)[j] * mo + ((const float*)&vmp)[j];
                    const float fd = ((const float*)&vdf)[j] * dy + ((const float*)&vdp)[j];
                    float v = ((const float*)&vya)[j] * sinf(fy)
                            + ((const float*)&vma)[j] * sinf(fm)
                            + ((const float*)&vda)[j] * sinf(fd);
                    ((unsigned short*)&b)[j] = vm ? f2bf(v) : 0;
                }
                *(ushort4*)&Xl[half][XIDX(m, S_DIM + j0)] = b;
            }
        }
        __syncthreads();

        // ---- MFMA + epilogue for this half
        if (mcnt > 0) {
            f32x4 acc[4][2];
            #pragma unroll
            for (int i = 0; i < 4; ++i)
                #pragma unroll
                for (int j = 0; j < 2; ++j) acc[i][j] = (f32x4)0.f;

            #pragma unroll
            for (int kk = 0; kk < 4; ++kk) {
                const int k0 = kk * 32;
                bf16x8 a[4];
                #pragma unroll
                for (int mt = 0; mt < 4; ++mt)
                    a[mt] = *(const bf16x8*)&Xl[half][XIDX(16 * mt + l15, k0 + 8 * g)];
                const bf16x8 b0 = *(const bf16x8*)&Wr[(size_t)((kk * 4 + wv) * 2 + 0) * 512 + lane * 8];
                const bf16x8 b1 = *(const bf16x8*)&Wr[(size_t)((kk * 4 + wv) * 2 + 1) * 512 + lane * 8];
                #pragma unroll
                for (int mt = 0; mt < 4; ++mt) {
                    acc[mt][0] = __builtin_amdgcn_mfma_f32_16x16x32_bf16(a[mt], b0, acc[mt][0], 0, 0, 0);
                    acc[mt][1] = __builtin_amdgcn_mfma_f32_16x16x32_bf16(a[mt], b1, acc[mt][1], 0, 0, 0);
                }
            }

            #pragma unroll
            for (int mt = 0; mt < 4; ++mt) {
                #pragma unroll
                for (int reg = 0; reg < 4; ++reg) {
                    const int ml = 16 * mt + 4 * g + reg;
                    if (ml < mcnt) {
                        const float v0 = acc[mt][0][reg] + bv0;
                        const float v1 = acc[mt][1][reg] + bv1;
                        const size_t row = (size_t)(start + hbase + ml) * DIM;
                        z_s[row + nn0] = v0;
                        z_s[row + nn1] = v1;
                        lsum0 += v0; lsq0 += v0 * v0;
                        lsum1 += v1; lsq1 += v1 * v1;
                    }
                }
            }
        }
        __syncthreads();
    }

    // ---- BN fold: intra-wave (over g), then cross-half via LDS -> global
    lsum0 += __shfl_xor(lsum0, 16); lsum0 += __shfl_xor(lsum0, 32);
    lsq0  += __shfl_xor(lsq0, 16);  lsq0  += __shfl_xor(lsq0, 32);
    lsum1 += __shfl_xor(lsum1, 16); lsum1 += __shfl_xor(lsum1, 32);
    lsq1  += __shfl_xor(lsq1, 16);  lsq1  += __shfl_xor(lsq1, 32);
    if (g == 0) {
        bnred[wid][0][l15][0] = lsum0; bnred[wid][0][l15][1] = lsq0;
        bnred[wid][1][l15][0] = lsum1; bnred[wid][1][l15][1] = lsq1;
    }
    __syncthreads();
    if (half == 0 && g == 0) {
        #pragma unroll
        for (int nt = 0; nt < 2; ++nt) {
            const int col = 32 * wv + 16 * nt + l15;
            const float s = bnred[wid][nt][l15][0] + bnred[wid + 4][nt][l15][0];
            const float q = bnred[wid][nt][l15][1] + bnred[wid + 4][nt][l15][1];
            float sc = 1.f, sh = 0.f;
            if (cnt > 1) {
                const float mean = s / (float)cnt;
                const float var  = fmaxf(q / (float)cnt - mean * mean, 0.f);
                const int gi = r * DIM + col;
                sc = gamma[gi] * rsqrtf(var + BN_EPS);
                sh = beta[gi] - mean * sc;
            }
            scale[r * DIM + col] = sc;
            shift[r * DIM + col] = sh;
        }
    }
}

// ---------------------------------------------------------------------------
// K5: pooling with fused BN affine + ReLU. One block per query; chain:
// eorder_src[e] -> rankpack -> {z_s row, scale/shift (L2-hot)}.
// ---------------------------------------------------------------------------
__global__ void k_pool2(const int* __restrict__ eorder_src, const int* __restrict__ dst_off,
                        const int* __restrict__ rankpack,
                        const float* __restrict__ z_s,
                        const float* __restrict__ scale, const float* __restrict__ shift,
                        float* __restrict__ emb)
{
    const int q = blockIdx.x;
    const int d = threadIdx.x;
    const int e0 = dst_off[q], e1 = dst_off[q + 1];
    float acc = 0.f;
    for (int e = e0; e < e1; ++e) {
        const int pk = rankpack[eorder_src[e]];
        const int p  = pk & 0x1FFFF;
        const int r  = pk >> 17;
        const float v = z_s[(size_t)p * DIM + d] * scale[r * DIM + d] + shift[r * DIM + d];
        acc += fmaxf(v, 0.f);
    }
    emb[(size_t)q * DIM + d] = (e1 > e0) ? acc / (float)(e1 - e0) : 0.f;
}

// ---------------------------------------------------------------------------
// K6: TransE scoring
// ---------------------------------------------------------------------------
__global__ void k_score(const int* __restrict__ head, const int* __restrict__ tail,
                        const int* __restrict__ rels,
                        const float* __restrict__ emb, const float* __restrict__ rel_embs,
                        float* __restrict__ out)
{
    const int b = blockIdx.x;
    const int d = threadIdx.x;
    const int h = head[b], tq = tail[b], r = rels[b];

    const float diff = emb[(size_t)h * DIM + d] + rel_embs[r * DIM + d]
                     - emb[(size_t)tq * DIM + d];
    float sq = diff * diff;
    for (int off = 32; off > 0; off >>= 1) sq += __shfl_down(sq, off);
    __shared__ float partial[2];
    if ((threadIdx.x & 63) == 0) partial[threadIdx.x >> 6] = sq;
    __syncthreads();
    if (threadIdx.x == 0) out[b] = -sqrtf(partial[0] + partial[1]);
}

// ---------------------------------------------------------------------------
extern "C" void kernel_launch(void* const* d_in, const int* in_sizes, int n_in,
                              void* d_out, int out_size, void* d_ws, size_t ws_size,
                              hipStream_t stream) {
    const int*   neighbor_idx = (const int*)  d_in[0];
    const int*   rel_id       = (const int*)  d_in[1];
    const float* years        = (const float*)d_in[2];
    const float* months       = (const float*)d_in[3];
    const float* days         = (const float*)d_in[4];
    const int*   pool_src     = (const int*)  d_in[5];
    const int*   pool_dst     = (const int*)  d_in[6];
    const int*   head_pos     = (const int*)  d_in[7];
    const int*   tail_pos     = (const int*)  d_in[8];
    const int*   rels         = (const int*)  d_in[9];
    const float* ent_embs     = (const float*)d_in[10];
    const float* y_freq       = (const float*)d_in[11];
    const float* y_phi        = (const float*)d_in[12];
    const float* y_amp        = (const float*)d_in[13];
    const float* m_freq       = (const float*)d_in[14];
    const float* m_phi        = (const float*)d_in[15];
    const float* m_amp        = (const float*)d_in[16];
    const float* d_freq       = (const float*)d_in[17];
    const float* d_phi        = (const float*)d_in[18];
    const float* d_amp        = (const float*)d_in[19];
    const float* rel_embs     = (const float*)d_in[20];
    const float* W            = (const float*)d_in[21];
    const float* bias         = (const float*)d_in[22];
    const float* gamma        = (const float*)d_in[23];
    const float* beta         = (const float*)d_in[24];

    float* out = (float*)d_out;

    // workspace layout (float units)
    float* ws = (float*)d_ws;
    size_t off = 0;
    unsigned short* Wfrag = (unsigned short*)(ws + off); off += (size_t)R2 * DIM * DIM / 2;  // 15 MB
    float* z_s   = ws + off; off += (size_t)N_NBR * DIM;   // 16 MB
    float* emb   = ws + off; off += (size_t)Q_ENT * DIM;
    float* scale = ws + off; off += (size_t)R2 * DIM;
    float* shift = ws + off; off += (size_t)R2 * DIM;
    int* hist_rel = (int*)(ws + off); off += R2;       // zero region (4556 ints)
    int* hist_dst = (int*)(ws + off); off += Q_ENT;
    int* offsets  = (int*)(ws + off); off += R2 + 1;
    int* cur_rel  = (int*)(ws + off); off += R2;
    int* dst_off  = (int*)(ws + off); off += Q_ENT + 1;
    int* cur_dst  = (int*)(ws + off); off += Q_ENT;
    int* order    = (int*)(ws + off); off += N_NBR;
    int* rankpack = (int*)(ws + off); off += N_NBR;
    int* eorder_src = (int*)(ws + off); off += E_EDGE;

    const int nzero4 = (R2 + Q_ENT + 3) / 4;   // 1139 int4
    k_zero<<<(nzero4 + 255) / 256, 256, 0, stream>>>(hist_rel, nzero4);

    k_front<<<R2 + (N_NBR + 255) / 256, 256, 0, stream>>>(
        W, Wfrag, rel_id, pool_dst, hist_rel, hist_dst);

    k_scan_both<<<2, 1024, 0, stream>>>(hist_rel, offsets, cur_rel,
                                        hist_dst, dst_off, cur_dst);

    k_scatter<<<(N_NBR + 255) / 256, 256, 0, stream>>>(rel_id, cur_rel, order, rankpack,
                                                       pool_src, pool_dst, cur_dst, eorder_src);

    k_matvec<<<R2, 512, 0, stream>>>(order, offsets, neighbor_idx,
                                     years, months, days, ent_embs,
                                     y_freq, y_phi, y_amp,
                                     m_freq, m_phi, m_amp,
                                     d_freq, d_phi, d_amp,
                                     Wfrag, bias, gamma, beta,
                                     z_s, scale, shift);

    k_pool2<<<Q_ENT, DIM, 0, stream>>>(eorder_src, dst_off, rankpack,
                                       z_s, scale, shift, emb);

    k_score<<<B_TRI, DIM, 0, stream>>>(head_pos, tail_pos, rels, emb, rel_embs, out);
}